// Round 1
// baseline (184.484 us; speedup 1.0000x reference)
//
#include <hip/hip_runtime.h>
#include <hip/hip_bf16.h>

namespace {

constexpr int IMG_H = 512;
constexpr int IMG_W = 512;
constexpr int BATCH = 64;
constexpr int RT = 16;                         // output rows per wave
constexpr int WAVES = 4;                       // waves per block
constexpr int ROWS_PER_BLOCK = RT * WAVES;     // 64
constexpr int BLOCKS_PER_IMG = IMG_H / ROWS_PER_BLOCK;  // 8
constexpr int GRID = BATCH * BLOCKS_PER_IMG;   // 512
constexpr int NPART = GRID * WAVES;            // 2048 partial sums
constexpr float C1 = 1.6384f;                  // (0.01*128)^2
constexpr float C2 = 14.7456f;                 // (0.03*128)^2
constexpr float INV121 = 1.0f / 121.0f;

__device__ __forceinline__ float shup1(float v) { return __shfl_up(v, 1, 64); }
__device__ __forceinline__ float shdn1(float v) { return __shfl_down(v, 1, 64); }

// Compute horizontal 11-box sums of {x, y, x*x, y*y, x*y} for image row r at
// this lane's 8 columns, and add (ADD) / subtract (!ADD) them into V[5][8].
// Out-of-range rows (zero padding) are a wave-uniform no-op.
template <bool ADD>
__device__ __forceinline__ void hrow_acc(const float* __restrict__ p1,
                                         const float* __restrict__ p2,
                                         int r, int lane, int c0,
                                         float V[5][8])
{
  if ((unsigned)r >= (unsigned)IMG_H) return;  // wave-uniform branch
  const float4* a1 = reinterpret_cast<const float4*>(p1 + (size_t)r * IMG_W + c0);
  const float4* a2 = reinterpret_cast<const float4*>(p2 + (size_t)r * IMG_W + c0);
  float4 xa = a1[0], xb = a1[1];
  float4 ya = a2[0], yb = a2[1];
  float ox[8] = {xa.x, xa.y, xa.z, xa.w, xb.x, xb.y, xb.z, xb.w};
  float oy[8] = {ya.x, ya.y, ya.z, ya.w, yb.x, yb.y, yb.z, yb.w};

  // 18-wide window: cols [c0-5, c0+12]; halo from neighbor lanes via shfl,
  // wave edges are the image's left/right zero padding.
  float xw[18], yw[18];
#pragma unroll
  for (int i = 0; i < 8; ++i) { xw[5 + i] = ox[i]; yw[5 + i] = oy[i]; }
  const bool l0 = (lane == 0), l63 = (lane == 63);
#pragma unroll
  for (int i = 0; i < 5; ++i) {
    float tx = shup1(ox[3 + i]), ty = shup1(oy[3 + i]);
    xw[i] = l0 ? 0.f : tx;
    yw[i] = l0 ? 0.f : ty;
    float bx = shdn1(ox[i]), by = shdn1(oy[i]);
    xw[13 + i] = l63 ? 0.f : bx;
    yw[13 + i] = l63 ? 0.f : by;
  }

#pragma unroll
  for (int q = 0; q < 5; ++q) {
    float w[18];
#pragma unroll
    for (int j = 0; j < 18; ++j) {
      float xv = xw[j], yv = yw[j];
      w[j] = (q == 0) ? xv
           : (q == 1) ? yv
           : (q == 2) ? xv * xv
           : (q == 3) ? yv * yv
           : xv * yv;
    }
    // sliding 11-wide sum over the 18-value window -> 8 outputs
    float h = w[0];
#pragma unroll
    for (int j = 1; j < 11; ++j) h += w[j];
    V[q][0] += ADD ? h : -h;
#pragma unroll
    for (int k = 1; k < 8; ++k) {
      h += w[k + 10] - w[k - 1];
      V[q][k] += ADD ? h : -h;
    }
  }
}

__device__ __forceinline__ float ssim_row(const float V[5][8])
{
  float rs = 0.f;
#pragma unroll
  for (int k = 0; k < 8; ++k) {
    float mu1 = V[0][k] * INV121;
    float mu2 = V[1][k] * INV121;
    float m11 = mu1 * mu1, m22 = mu2 * mu2, m12 = mu1 * mu2;
    float s1  = V[2][k] * INV121 - m11;
    float s2  = V[3][k] * INV121 - m22;
    float s12 = V[4][k] * INV121 - m12;
    float n1 = 2.f * m12 + C1;
    float n2 = 2.f * s12 + C2;
    float d1 = m11 + m22 + C1;
    float d2 = s1 + s2 + C2;
    float den = d1 * d2;                 // >= C1*C2 > 0
    float rc = __builtin_amdgcn_rcpf(den);
    rc = rc * (2.f - den * rc);          // one Newton step
    rs += (n1 * n2) * rc;
  }
  return rs;
}

} // namespace

__global__ __launch_bounds__(256, 2) void ssim_main(
    const float* __restrict__ img1, const float* __restrict__ img2,
    float* __restrict__ partials)
{
  const int tid = threadIdx.x;
  const int wave = tid >> 6;
  const int lane = tid & 63;
  const int gb = blockIdx.x;
  const int b  = gb >> 3;                 // batch (8 row-blocks per image)
  const int rb = gb & 7;
  const int y0 = rb * ROWS_PER_BLOCK + wave * RT;
  const int c0 = lane * 8;
  const float* p1 = img1 + (size_t)b * IMG_H * IMG_W;
  const float* p2 = img2 + (size_t)b * IMG_H * IMG_W;

  float V[5][8];
#pragma unroll
  for (int q = 0; q < 5; ++q)
#pragma unroll
    for (int k = 0; k < 8; ++k) V[q][k] = 0.f;

  // warm-up: V = sum of horizontal sums over rows [y0-5, y0+5]
#pragma unroll 1
  for (int d = -5; d <= 5; ++d) hrow_acc<true>(p1, p2, y0 + d, lane, c0, V);

  float acc = ssim_row(V);

  // slide the 11-row vertical window down the strip
#pragma unroll 1
  for (int y = y0 + 1; y < y0 + RT; ++y) {
    hrow_acc<true >(p1, p2, y + 5, lane, c0, V);
    hrow_acc<false>(p1, p2, y - 6, lane, c0, V);
    acc += ssim_row(V);
  }

  // wave reduction -> one float partial per wave
#pragma unroll
  for (int off = 32; off > 0; off >>= 1) acc += __shfl_down(acc, off, 64);
  if (lane == 0) partials[gb * WAVES + wave] = acc;
}

__global__ void ssim_reduce(const float* __restrict__ partials,
                            float* __restrict__ out)
{
  __shared__ double sd[256];
  const int tid = threadIdx.x;
  double s = 0.0;
  for (int i = tid; i < NPART; i += 256) s += (double)partials[i];
  sd[tid] = s;
  __syncthreads();
  for (int st = 128; st > 0; st >>= 1) {
    if (tid < st) sd[tid] += sd[tid + st];
    __syncthreads();
  }
  if (tid == 0) {
    double mean = sd[0] * (1.0 / 16777216.0);  // 64*512*512
    out[0] = (float)(1.0 - mean);
  }
}

extern "C" void kernel_launch(void* const* d_in, const int* in_sizes, int n_in,
                              void* d_out, int out_size, void* d_ws, size_t ws_size,
                              hipStream_t stream)
{
  const float* img1 = (const float*)d_in[0];
  const float* img2 = (const float*)d_in[1];
  // d_in[2] is the uniform 1/121 window; folded into INV121.
  float* out = (float*)d_out;
  float* partials = (float*)d_ws;  // NPART floats, fully overwritten each call

  ssim_main<<<dim3(GRID), dim3(256), 0, stream>>>(img1, img2, partials);
  ssim_reduce<<<dim3(1), dim3(256), 0, stream>>>(partials, out);
}